// Round 3
// baseline (286.551 us; speedup 1.0000x reference)
//
#include <hip/hip_runtime.h>
#include <cstdint>
#include <cstddef>

#define B_ 16
#define S_ 2048
#define D_ 128
#define M_ 16            // q-rows per block
#define NW 8             // waves per block
#define CPW (S_ / NW)    // score columns per wave = 256
#define PSTR 2050        // p_lds row stride in halves: 1025 dwords == 1 mod 32

typedef float  f32x4 __attribute__((ext_vector_type(4)));
typedef _Float16 f16x8 __attribute__((ext_vector_type(8)));
typedef _Float16 f16x4 __attribute__((ext_vector_type(4)));

// log2(e) / sqrt(128)
#define SCALE_ 0.12751743f

#define NE_ ((size_t)B_ * S_ * D_)   // 4,194,304 per tensor

// ---------------- merged pre-pass ----------------
// blocks [0,4096): V [b][k][d] -> Vt [b][d][k] f16 (32x32 tiles via LDS)
// blocks [4096,5120): Q f32 -> f16
// blocks [5120,6144): K f32 -> f16
__global__ void prepass_kernel(const float* __restrict__ Q,
                               const float* __restrict__ K,
                               const float* __restrict__ V,
                               _Float16* __restrict__ Qh,
                               _Float16* __restrict__ Kh,
                               _Float16* __restrict__ Vt) {
  __shared__ _Float16 t[32][33];
  const int blk = blockIdx.x;
  if (blk < 4096) {
    int dt = blk & 3;          // 4 d-tiles of 32
    int kt = (blk >> 2) & 63;  // 64 k-tiles of 32
    int b  = blk >> 8;         // 16 batches
    int tx = threadIdx.x & 31, ty = threadIdx.x >> 5;  // 32 x 8
    int k0 = kt * 32, d0 = dt * 32;
    for (int i = 0; i < 4; ++i) {
      int kk = ty + i * 8;
      t[kk][tx] = (_Float16)V[((size_t)b * S_ + k0 + kk) * D_ + d0 + tx];
    }
    __syncthreads();
    for (int i = 0; i < 4; ++i) {
      int dd = ty + i * 8;
      Vt[((size_t)b * D_ + d0 + dd) * S_ + k0 + tx] = t[tx][dd];
    }
  } else {
    int rel = blk - 4096;
    const float* src;
    _Float16* dst;
    if (rel < 1024) { src = Q; dst = Qh; }
    else            { src = K; dst = Kh; rel -= 1024; }
    const int n4 = (int)(NE_ / 4);
    for (int i = rel * 256 + (int)threadIdx.x; i < n4; i += 1024 * 256) {
      f32x4 v = ((const f32x4*)src)[i];
      f16x4 h;
      for (int j = 0; j < 4; ++j) h[j] = (_Float16)v[j];
      ((f16x4*)dst)[i] = h;
    }
  }
}

// ---------------- fused attention ----------------
template <bool WS>
__global__ __launch_bounds__(512, 4)
void attn_fused(const float* __restrict__ Qf, const float* __restrict__ Kf,
                const float* __restrict__ Vf,
                const _Float16* __restrict__ Qh, const _Float16* __restrict__ Kh,
                const _Float16* __restrict__ Vt,
                float* __restrict__ outO, float* __restrict__ outA) {
  __shared__ _Float16 p_lds[M_][PSTR];   // unnormalized exp scores, fp16 (~65.6 KB)
  __shared__ float wsum[NW][M_];
  __shared__ float inv_l[M_];

  const int tid  = threadIdx.x;
  const int w    = tid >> 6;
  const int lane = tid & 63;
  const int lg   = lane >> 4;   // 0..3
  const int lr   = lane & 15;   // 0..15
  const int blk  = blockIdx.x;
  const int b    = blk & 15;    // batch -> XCD = b&7 (2 batches per XCD L2)
  const int qt   = blk >> 4;    // 0..127
  const int q0   = qt * M_;

  // ---- Q fragments: A[m=lr][k = 32*kk + 8*lg + j] ----
  f16x8 aq[4];
  {
    const int row = q0 + lr;
    for (int kk = 0; kk < 4; ++kk) {
      const size_t off = ((size_t)b * S_ + row) * D_ + kk * 32 + lg * 8;
      if constexpr (WS) {
        aq[kk] = *(const f16x8*)(Qh + off);
      } else {
        const float* p = Qf + off;
        f32x4 v0 = *(const f32x4*)p, v1 = *(const f32x4*)(p + 4);
        f16x8 a;
        for (int j = 0; j < 4; ++j) { a[j] = (_Float16)v0[j]; a[4 + j] = (_Float16)v1[j]; }
        aq[kk] = a;
      }
    }
  }

  // ---- Phase 1: S = QK^T / temper, P = exp(S), row partial sums ----
  float psum[4] = {};
#pragma unroll 2
  for (int ct = 0; ct < CPW / 16; ++ct) {
    const int col0 = w * CPW + ct * 16;
    f32x4 acc = {0.f, 0.f, 0.f, 0.f};
    for (int kk = 0; kk < 4; ++kk) {
      // B[k = 32*kk + 8*lg + j][n = col0 + lr] = K[col0+lr][...]
      f16x8 bk;
      const size_t off = ((size_t)b * S_ + col0 + lr) * D_ + kk * 32 + lg * 8;
      if constexpr (WS) {
        bk = *(const f16x8*)(Kh + off);
      } else {
        const float* p = Kf + off;
        f32x4 v0 = *(const f32x4*)p, v1 = *(const f32x4*)(p + 4);
        for (int j = 0; j < 4; ++j) { bk[j] = (_Float16)v0[j]; bk[4 + j] = (_Float16)v1[j]; }
      }
      acc = __builtin_amdgcn_mfma_f32_16x16x32_f16(aq[kk], bk, acc, 0, 0, 0);
    }
    // D layout: col = lane&15 (score col), row = 4*(lane>>4) + r (q row)
    for (int r = 0; r < 4; ++r) {
      float p0 = exp2f(acc[r] * SCALE_);
      psum[r] += p0;
      p_lds[lg * 4 + r][col0 + lr] = (_Float16)p0;
    }
  }

  // deterministic row-sum reduction
  for (int r = 0; r < 4; ++r) {
    float s = psum[r];
    s += __shfl_xor(s, 1);
    s += __shfl_xor(s, 2);
    s += __shfl_xor(s, 4);
    s += __shfl_xor(s, 8);
    if (lr == 0) wsum[w][lg * 4 + r] = s;
  }
  __syncthreads();
  if (tid < M_) {
    float s = 0.f;
    for (int i = 0; i < NW; ++i) s += wsum[i][tid];
    inv_l[tid] = 1.0f / s;
  }
  __syncthreads();

  // ---- Phase 2: pure PV (loads + MFMA only) ----
  const int d0v = w * 16;
  f32x4 o = {0.f, 0.f, 0.f, 0.f};

#pragma unroll 4
  for (int kb = 0; kb < S_ / 32; ++kb) {  // 64 iterations
    const int k0 = kb * 32;
    // B[k = k0 + 8*lg + j][n = d0v + lr] = V[k][d] = Vt[d][k]
    f16x8 bv;
    if constexpr (WS) {
      bv = *(const f16x8*)(Vt + ((size_t)b * D_ + d0v + lr) * S_ + k0 + lg * 8);
    } else {
      const float* vp = Vf + ((size_t)b * S_ + k0 + lg * 8) * D_ + d0v + lr;
      for (int j = 0; j < 8; ++j) bv[j] = (_Float16)vp[(size_t)j * D_];
    }
    // A[m = lr][k = k0 + 8*lg + j] from LDS (contiguous 16B)
    f16x8 ap = *(const f16x8*)(&p_lds[lr][k0 + lg * 8]);
    o = __builtin_amdgcn_mfma_f32_16x16x32_f16(ap, bv, o, 0, 0, 0);
  }

  // ---- O writeback: row = 4*lg + r, col = d0v + lr ----
  for (int r = 0; r < 4; ++r) {
    const int row = lg * 4 + r;
    outO[((size_t)b * S_ + q0 + row) * D_ + d0v + lr] = o[r] * inv_l[row];
  }

  // ---- Phase 3: attn stores, wide + nontemporal (don't evict K/Vt from L2).
  //      8 rounds x (2 rows x 256 threads); each thread: b128 LDS read,
  //      normalize, two f32x4 NT stores (fire-and-forget). ----
#pragma unroll 2
  for (int rd = 0; rd < 8; ++rd) {
    const int row = (tid >> 8) + rd * 2;
    const int c0  = (tid & 255) * 8;
    f16x8 pv = *(const f16x8*)(&p_lds[row][c0]);
    const float inv = inv_l[row];
    f32x4 a0, a1;
    for (int j = 0; j < 4; ++j) { a0[j] = (float)pv[j] * inv; a1[j] = (float)pv[4 + j] * inv; }
    float* dst = outA + ((size_t)b * S_ + q0 + row) * S_ + c0;
    __builtin_nontemporal_store(a0, (f32x4*)dst);
    __builtin_nontemporal_store(a1, (f32x4*)(dst + 4));
  }
}

extern "C" void kernel_launch(void* const* d_in, const int* in_sizes, int n_in,
                              void* d_out, int out_size, void* d_ws, size_t ws_size,
                              hipStream_t stream) {
  const float* Q = (const float*)d_in[0];
  const float* K = (const float*)d_in[1];
  const float* V = (const float*)d_in[2];
  float* outO = (float*)d_out;
  float* outA = outO + NE_;

  const size_t need = 3 * NE_ * sizeof(_Float16);   // 24 MiB

  const int nblk = B_ * S_ / M_;  // 2048

  if (ws_size >= need) {
    _Float16* Qh = (_Float16*)d_ws;
    _Float16* Kh = Qh + NE_;
    _Float16* Vt = Kh + NE_;
    prepass_kernel<<<6144, 256, 0, stream>>>(Q, K, V, Qh, Kh, Vt);
    attn_fused<true><<<nblk, 512, 0, stream>>>(nullptr, nullptr, nullptr,
                                               Qh, Kh, Vt, outO, outA);
  } else {
    attn_fused<false><<<nblk, 512, 0, stream>>>(Q, K, V,
                                                nullptr, nullptr, nullptr,
                                                outO, outA);
  }
}

// Round 4
// 158.324 us; speedup vs baseline: 1.8099x; 1.8099x over previous
//
#include <hip/hip_runtime.h>
#include <cstdint>
#include <cstddef>

#define B_ 16
#define S_ 2048
#define D_ 128
#define M_ 32            // q-rows per block
#define NW 8             // waves per block
#define CPW (S_ / NW)    // score columns per wave = 256

typedef float  f32x4 __attribute__((ext_vector_type(4)));
typedef _Float16 f16x8 __attribute__((ext_vector_type(8)));
typedef _Float16 f16x4 __attribute__((ext_vector_type(4)));

// log2(e) / sqrt(128)
#define SCALE_ 0.12751743f

#define NE_ ((size_t)B_ * S_ * D_)   // 4,194,304 per tensor

// ---- swizzled P LDS addressing -------------------------------------------
// P stored as [32 rows][2048 halves], row stride 4096B (power of 2), with a
// 16B-chunk XOR swizzle: chunk' = chunk ^ (row & 7). All three access
// patterns (b16 scatter writes, b128 A-frag reads across 16 rows, b64/b128
// row-sweep reads) land at or near the minimum LDS cycle count.
__device__ __forceinline__ int p_idx(int row, int col) {
  return row * 2048 + ((((col) >> 3) ^ (row & 7)) << 3) + ((col) & 7);
}

// ---------------- pre-pass ----------------
// blocks [0,4096): V [b][k][d] -> Vt [b][d][k] f16 (32x32 tiles via LDS)
// blocks [4096,5120): K f32 -> f16
__global__ void prepass_kernel(const float* __restrict__ K,
                               const float* __restrict__ V,
                               _Float16* __restrict__ Kh,
                               _Float16* __restrict__ Vt) {
  __shared__ _Float16 t[32][33];
  const int blk = blockIdx.x;
  if (blk < 4096) {
    int dt = blk & 3;          // 4 d-tiles of 32
    int kt = (blk >> 2) & 63;  // 64 k-tiles of 32
    int b  = blk >> 8;         // 16 batches
    int tx = threadIdx.x & 31, ty = threadIdx.x >> 5;  // 32 x 8
    int k0 = kt * 32, d0 = dt * 32;
    for (int i = 0; i < 4; ++i) {
      int kk = ty + i * 8;
      t[kk][tx] = (_Float16)V[((size_t)b * S_ + k0 + kk) * D_ + d0 + tx];
    }
    __syncthreads();
    for (int i = 0; i < 4; ++i) {
      int dd = ty + i * 8;
      Vt[((size_t)b * D_ + d0 + dd) * S_ + k0 + tx] = t[tx][dd];
    }
  } else {
    int rel = blk - 4096;      // 0..1023
    const int n4 = (int)(NE_ / 4);
    for (int i = rel * 256 + (int)threadIdx.x; i < n4; i += 1024 * 256) {
      f32x4 v = ((const f32x4*)K)[i];
      f16x4 h;
      for (int j = 0; j < 4; ++j) h[j] = (_Float16)v[j];
      ((f16x4*)Kh)[i] = h;
    }
  }
}

// ---------------- fused attention ----------------
template <bool WS>
__global__ __launch_bounds__(512, 2)
void attn_fused(const float* __restrict__ Qf, const float* __restrict__ Kf,
                const float* __restrict__ Vf,
                const _Float16* __restrict__ Kh, const _Float16* __restrict__ Vt,
                float* __restrict__ outO, float* __restrict__ outA) {
  __shared__ _Float16 p_lds[M_ * 2048];  // 128 KB, swizzled
  __shared__ float wsum[NW][M_];
  __shared__ float inv_l[M_];

  const int tid  = threadIdx.x;
  const int w    = tid >> 6;
  const int lane = tid & 63;
  const int lg   = lane >> 4;   // 0..3
  const int lr   = lane & 15;   // 0..15
  const int blk  = blockIdx.x;
  const int b    = blk & 15;    // batch -> XCD = b&7 (2 batches per XCD L2)
  const int qt   = blk >> 4;    // 0..63
  const int q0   = qt * M_;

  // ---- Q fragments from f32 (once per block; no prepass needed for Q) ----
  // A[m=lr][k = 32*kk + 8*lg + j], two 16-row halves
  f16x8 aq[2][4];
  for (int h = 0; h < 2; ++h) {
    const int row = q0 + h * 16 + lr;
    for (int kk = 0; kk < 4; ++kk) {
      const float* p = Qf + ((size_t)b * S_ + row) * D_ + kk * 32 + lg * 8;
      f32x4 v0 = *(const f32x4*)p, v1 = *(const f32x4*)(p + 4);
      f16x8 a;
      for (int j = 0; j < 4; ++j) { a[j] = (_Float16)v0[j]; a[4 + j] = (_Float16)v1[j]; }
      aq[h][kk] = a;
    }
  }

  // ---- Phase 1: S = QK^T / temper, P = exp(S), row partial sums ----
  float psum[2][4] = {};
#pragma unroll 2
  for (int ct = 0; ct < CPW / 16; ++ct) {
    const int col0 = w * CPW + ct * 16;
    f32x4 acc0 = {0.f, 0.f, 0.f, 0.f}, acc1 = {0.f, 0.f, 0.f, 0.f};
    for (int kk = 0; kk < 4; ++kk) {
      // B[k = 32*kk + 8*lg + j][n = col0 + lr] = K[col0+lr][...]
      f16x8 bk;
      const size_t off = ((size_t)b * S_ + col0 + lr) * D_ + kk * 32 + lg * 8;
      if constexpr (WS) {
        bk = *(const f16x8*)(Kh + off);
      } else {
        const float* p = Kf + off;
        f32x4 v0 = *(const f32x4*)p, v1 = *(const f32x4*)(p + 4);
        for (int j = 0; j < 4; ++j) { bk[j] = (_Float16)v0[j]; bk[4 + j] = (_Float16)v1[j]; }
      }
      acc0 = __builtin_amdgcn_mfma_f32_16x16x32_f16(aq[0][kk], bk, acc0, 0, 0, 0);
      acc1 = __builtin_amdgcn_mfma_f32_16x16x32_f16(aq[1][kk], bk, acc1, 0, 0, 0);
    }
    // D layout: col = lane&15 (score col), row = 4*(lane>>4) + r (q row)
    const int col = col0 + lr;
    for (int r = 0; r < 4; ++r) {
      float p0 = __builtin_amdgcn_exp2f(acc0[r] * SCALE_);
      float p1 = __builtin_amdgcn_exp2f(acc1[r] * SCALE_);
      psum[0][r] += p0;
      psum[1][r] += p1;
      p_lds[p_idx(lg * 4 + r, col)]      = (_Float16)p0;
      p_lds[p_idx(16 + lg * 4 + r, col)] = (_Float16)p1;
    }
  }

  // deterministic row-sum reduction: shfl within 16-lane groups, fixed-order LDS
  for (int h = 0; h < 2; ++h)
    for (int r = 0; r < 4; ++r) {
      float s = psum[h][r];
      s += __shfl_xor(s, 1);
      s += __shfl_xor(s, 2);
      s += __shfl_xor(s, 4);
      s += __shfl_xor(s, 8);
      if (lr == 0) wsum[w][h * 16 + lg * 4 + r] = s;
    }
  __syncthreads();
  if (tid < M_) {
    float s = 0.f;
    for (int i = 0; i < NW; ++i) s += wsum[i][tid];
    inv_l[tid] = 1.0f / s;
  }
  __syncthreads();

  // ---- Phase 2+3 fused: PV MFMA interleaved with NT attn stores ----
  const int d0v = w * 16;
  f32x4 o0 = {0.f, 0.f, 0.f, 0.f}, o1 = {0.f, 0.f, 0.f, 0.f};
  const _Float16* vtbase = WS ? (Vt + ((size_t)b * D_ + d0v + lr) * S_) : nullptr;

#pragma unroll 2
  for (int kb = 0; kb < S_ / 32; ++kb) {  // 64 iterations
    const int k0 = kb * 32;
    // B[k = k0 + 8*lg + j][n = d0v + lr] = V[k][d] = Vt[d][k]
    f16x8 bv;
    if constexpr (WS) {
      bv = *(const f16x8*)(vtbase + k0 + lg * 8);
    } else {
      const float* vp = Vf + ((size_t)b * S_ + k0 + lg * 8) * D_ + d0v + lr;
      for (int j = 0; j < 8; ++j) bv[j] = (_Float16)vp[(size_t)j * D_];
    }
    // A[m = lr][k = k0 + 8*lg + j] from swizzled LDS (16B chunk-aligned)
    const int cchunk = ((k0 + lg * 8) >> 3) ^ (lr & 7);
    f16x8 ap0 = *(const f16x8*)(&p_lds[lr * 2048 + (cchunk << 3)]);
    f16x8 ap1 = *(const f16x8*)(&p_lds[(16 + lr) * 2048 + (cchunk << 3)]);
    o0 = __builtin_amdgcn_mfma_f32_16x16x32_f16(ap0, bv, o0, 0, 0, 0);
    o1 = __builtin_amdgcn_mfma_f32_16x16x32_f16(ap1, bv, o1, 0, 0, 0);

    // interleaved attn store: every 2nd iter, 1 row; wave covers 256 cols
    if (kb & 1) {
      const int row = kb >> 1;  // 0..31
      const int c0  = w * CPW + lane * 4;
      const int idx = row * 2048 +
                      ((((c0) >> 3) ^ (row & 7)) << 3) + (c0 & 7);
      f16x4 pv = *(const f16x4*)(&p_lds[idx]);
      const float inv = inv_l[row];
      f32x4 av;
      for (int j = 0; j < 4; ++j) av[j] = (float)pv[j] * inv;
      float* dst = outA + ((size_t)b * S_ + q0 + row) * S_ + c0;
      __builtin_nontemporal_store(av, (f32x4*)dst);
    }
  }

  // ---- O writeback: row = h*16 + 4*lg + r, col = d0v + lr ----
  for (int h = 0; h < 2; ++h)
    for (int r = 0; r < 4; ++r) {
      const int row = h * 16 + lg * 4 + r;
      const float ov = (h ? o1[r] : o0[r]) * inv_l[row];
      outO[((size_t)b * S_ + q0 + row) * D_ + d0v + lr] = ov;
    }
}

extern "C" void kernel_launch(void* const* d_in, const int* in_sizes, int n_in,
                              void* d_out, int out_size, void* d_ws, size_t ws_size,
                              hipStream_t stream) {
  const float* Q = (const float*)d_in[0];
  const float* K = (const float*)d_in[1];
  const float* V = (const float*)d_in[2];
  float* outO = (float*)d_out;
  float* outA = outO + NE_;

  const size_t need = 2 * NE_ * sizeof(_Float16);   // 16 MiB (Kh + Vt)

  const int nblk = B_ * S_ / M_;  // 1024

  if (ws_size >= need) {
    _Float16* Kh = (_Float16*)d_ws;
    _Float16* Vt = Kh + NE_;
    prepass_kernel<<<5120, 256, 0, stream>>>(K, V, Kh, Vt);
    attn_fused<true><<<nblk, 512, 0, stream>>>(Q, nullptr, nullptr,
                                               Kh, Vt, outO, outA);
  } else {
    attn_fused<false><<<nblk, 512, 0, stream>>>(Q, K, V,
                                                nullptr, nullptr, outO, outA);
  }
}